// Round 1
// baseline (122.110 us; speedup 1.0000x reference)
//
#include <hip/hip_runtime.h>

#define S_ 2048
#define D_ 64
#define QBLK 128
#define KVBLK 64

typedef __bf16 bf16x4 __attribute__((ext_vector_type(4)));
typedef __bf16 bf16x8 __attribute__((ext_vector_type(8)));
typedef float f32x4 __attribute__((ext_vector_type(4)));

__global__ __launch_bounds__(256, 2)
void fa_fwd(const float* __restrict__ qg, const float* __restrict__ kg,
            const float* __restrict__ vg, float* __restrict__ og) {
    __shared__ __attribute__((aligned(16))) __bf16 K_lds[64 * 64];
    __shared__ __attribute__((aligned(16))) __bf16 V_lds[64 * 64];  // transposed: [d][key]
    __shared__ __attribute__((aligned(16))) __bf16 P_lds[8][16 * 64]; // per (wave,qset)

    const int tid  = threadIdx.x;
    const int lane = tid & 63;
    const int wv   = tid >> 6;     // wave 0..3
    const int lo   = lane & 15;
    const int hi   = lane >> 4;    // 0..3

    const int x  = blockIdx.x;             // 0..15
    const int bh = blockIdx.y;             // 0..31
    // pair heavy+light q-tiles on the same CU (c and c+256 differ in bh bit4)
    const int qt = ((bh >> 4) & 1) ? (15 - x) : x;
    const int q0 = qt * QBLK;

    const size_t base = (size_t)bh * (S_ * D_);
    const float* Q = qg + base;
    const float* K = kg + base;
    const float* V = vg + base;
    float*       O = og + base;

    // ---- Q fragments (A-layout), pre-scaled by 1/sqrt(64) ----
    bf16x8 qf[2][2];
    #pragma unroll
    for (int qs = 0; qs < 2; ++qs) {
        const int row = q0 + wv * 32 + qs * 16 + lo;
        const float* Qr = Q + (size_t)row * D_;
        #pragma unroll
        for (int c = 0; c < 2; ++c) {
            const int d0 = c * 32 + hi * 8;
            f32x4 a = *(const f32x4*)(Qr + d0);
            f32x4 b = *(const f32x4*)(Qr + d0 + 4);
            bf16x8 f;
            #pragma unroll
            for (int j = 0; j < 4; ++j) {
                f[j]     = (__bf16)(a[j] * 0.125f);
                f[4 + j] = (__bf16)(b[j] * 0.125f);
            }
            qf[qs][c] = f;
        }
    }

    f32x4 acc[2][4];
    float m_r[2][4], l_r[2][4];
    #pragma unroll
    for (int qs = 0; qs < 2; ++qs)
        #pragma unroll
        for (int i = 0; i < 4; ++i) {
            acc[qs][i] = (f32x4){0.f, 0.f, 0.f, 0.f};
            m_r[qs][i] = -1e30f;
            l_r[qs][i] = 0.f;
        }

    const int keyg = tid >> 4;  // 0..15 -> keys 4*keyg..+3
    const int dseg = tid & 15;  // d segment of 4
    const int ntiles = 2 * qt + 2;

    for (int t = 0; t < ntiles; ++t) {
        const int kv0 = t * KVBLK;
        __syncthreads();
        // ---- stage K (row-major) and V (transposed) into LDS as bf16, swizzled ----
        {
            const float* Kt = K + (size_t)kv0 * D_ + dseg * 4;
            const float* Vt = V + (size_t)kv0 * D_ + dseg * 4;
            f32x4 rk[4], rv[4];
            #pragma unroll
            for (int i = 0; i < 4; ++i) {
                rk[i] = *(const f32x4*)(Kt + (4 * keyg + i) * D_);
                rv[i] = *(const f32x4*)(Vt + (4 * keyg + i) * D_);
            }
            #pragma unroll
            for (int i = 0; i < 4; ++i) {
                const int key  = 4 * keyg + i;
                const int eoff = key * 64 + ((((dseg * 8) ^ ((key & 7) << 4))) >> 1);
                bf16x4 pk;
                #pragma unroll
                for (int j = 0; j < 4; ++j) pk[j] = (__bf16)rk[i][j];
                *(bf16x4*)(&K_lds[eoff]) = pk;
            }
            #pragma unroll
            for (int j = 0; j < 4; ++j) {
                const int d    = dseg * 4 + j;
                const int eoff = d * 64 + ((((keyg * 8) ^ ((d & 7) << 4))) >> 1);
                bf16x4 pv;
                #pragma unroll
                for (int i = 0; i < 4; ++i) pv[i] = (__bf16)rv[i][j];
                *(bf16x4*)(&V_lds[eoff]) = pv;
            }
        }
        __syncthreads();

        // ---- compute ----
        const int rb0 = q0 + wv * 32;
        const bool act0 = (kv0 <= rb0 + 15);
        const bool act1 = (kv0 <= rb0 + 31);
        if (act1) {
            bool act[2] = {act0, act1};
            float sv[2][4][4];
            // QK^T: K-frags shared across both q-sets
            #pragma unroll
            for (int kb = 0; kb < 4; ++kb) {
                const int key = kb * 16 + lo;
                bf16x8 kf[2];
                #pragma unroll
                for (int c = 0; c < 2; ++c) {
                    const int o = (c * 64 + hi * 16) ^ ((key & 7) << 4);
                    kf[c] = *(const bf16x8*)(&K_lds[key * 64 + (o >> 1)]);
                }
                #pragma unroll
                for (int qs = 0; qs < 2; ++qs) {
                    if (!act[qs]) continue;
                    f32x4 s = {0.f, 0.f, 0.f, 0.f};
                    s = __builtin_amdgcn_mfma_f32_16x16x32_bf16(qf[qs][0], kf[0], s, 0, 0, 0);
                    s = __builtin_amdgcn_mfma_f32_16x16x32_bf16(qf[qs][1], kf[1], s, 0, 0, 0);
                    const int rb = rb0 + qs * 16;
                    const bool needmask = (kv0 + KVBLK - 1 > rb);
                    #pragma unroll
                    for (int r = 0; r < 4; ++r) {
                        float xv = s[r];
                        if (needmask && (kv0 + key > rb + hi * 4 + r)) xv = -1e30f;
                        sv[qs][kb][r] = xv;
                    }
                }
            }
            // online softmax (rows live on 16-lane groups)
            #pragma unroll
            for (int qs = 0; qs < 2; ++qs) {
                if (!act[qs]) continue;
                #pragma unroll
                for (int r = 0; r < 4; ++r) {
                    float mx = fmaxf(fmaxf(sv[qs][0][r], sv[qs][1][r]),
                                     fmaxf(sv[qs][2][r], sv[qs][3][r]));
                    mx = fmaxf(mx, __shfl_xor(mx, 1));
                    mx = fmaxf(mx, __shfl_xor(mx, 2));
                    mx = fmaxf(mx, __shfl_xor(mx, 4));
                    mx = fmaxf(mx, __shfl_xor(mx, 8));
                    const float mold = m_r[qs][r];
                    const float newm = fmaxf(mold, mx);
                    const float corr = __expf(mold - newm);
                    m_r[qs][r] = newm;
                    const int prow = hi * 4 + r;
                    float rs = 0.f;
                    #pragma unroll
                    for (int kb = 0; kb < 4; ++kb) {
                        const float p = __expf(sv[qs][kb][r] - newm);
                        rs += p;
                        const int cb = (kb * 32 + lo * 2) ^ ((prow & 7) << 4);
                        P_lds[wv * 2 + qs][prow * 64 + (cb >> 1)] = (__bf16)p;
                    }
                    rs += __shfl_xor(rs, 1);
                    rs += __shfl_xor(rs, 2);
                    rs += __shfl_xor(rs, 4);
                    rs += __shfl_xor(rs, 8);
                    l_r[qs][r] = l_r[qs][r] * corr + rs;
                    #pragma unroll
                    for (int db = 0; db < 4; ++db) acc[qs][db][r] *= corr;
                }
            }
            // PV: V-frags shared across both q-sets
            bf16x8 pa[2][2];
            #pragma unroll
            for (int qs = 0; qs < 2; ++qs) {
                if (!act[qs]) continue;
                #pragma unroll
                for (int c = 0; c < 2; ++c) {
                    const int o = (c * 64 + hi * 16) ^ ((lo & 7) << 4);
                    pa[qs][c] = *(const bf16x8*)(&P_lds[wv * 2 + qs][lo * 64 + (o >> 1)]);
                }
            }
            #pragma unroll
            for (int db = 0; db < 4; ++db) {
                const int d = db * 16 + lo;
                #pragma unroll
                for (int c = 0; c < 2; ++c) {
                    const int o = (c * 64 + hi * 16) ^ ((d & 7) << 4);
                    bf16x8 vb = *(const bf16x8*)(&V_lds[d * 64 + (o >> 1)]);
                    #pragma unroll
                    for (int qs = 0; qs < 2; ++qs) {
                        if (!act[qs]) continue;
                        acc[qs][db] = __builtin_amdgcn_mfma_f32_16x16x32_bf16(
                            pa[qs][c], vb, acc[qs][db], 0, 0, 0);
                    }
                }
            }
        }
    }

    // ---- epilogue: O = acc / l ----
    #pragma unroll
    for (int qs = 0; qs < 2; ++qs) {
        #pragma unroll
        for (int r = 0; r < 4; ++r) {
            const int row = q0 + wv * 32 + qs * 16 + hi * 4 + r;
            const float inv = 1.0f / l_r[qs][r];
            float* Or = O + (size_t)row * D_;
            #pragma unroll
            for (int db = 0; db < 4; ++db)
                Or[db * 16 + lo] = acc[qs][db][r] * inv;
        }
    }
}

extern "C" void kernel_launch(void* const* d_in, const int* in_sizes, int n_in,
                              void* d_out, int out_size, void* d_ws, size_t ws_size,
                              hipStream_t stream) {
    const float* q = (const float*)d_in[0];
    const float* k = (const float*)d_in[1];
    const float* v = (const float*)d_in[2];
    // d_in[3] = causal mask, structure known -> unused
    float* out = (float*)d_out;
    dim3 grid(16, 32, 1);
    dim3 block(256, 1, 1);
    fa_fwd<<<grid, block, 0, stream>>>(q, k, v, out);
}

// Round 2
// 115.609 us; speedup vs baseline: 1.0562x; 1.0562x over previous
//
#include <hip/hip_runtime.h>

#define S_ 2048
#define D_ 64

typedef __bf16 bf16x4 __attribute__((ext_vector_type(4)));
typedef __bf16 bf16x8 __attribute__((ext_vector_type(8)));
typedef float f32x4 __attribute__((ext_vector_type(4)));

__global__ __launch_bounds__(256, 4)
void fa_fwd(const float* __restrict__ qg, const float* __restrict__ kg,
            const float* __restrict__ vg, float* __restrict__ og) {
    // double-buffered K (row-major [key][d]) and V (transposed [d][key]), XOR-swizzled
    __shared__ __attribute__((aligned(16))) __bf16 K_lds[2][64 * 64];
    __shared__ __attribute__((aligned(16))) __bf16 V_lds[2][64 * 64];
    __shared__ __attribute__((aligned(16))) __bf16 P_lds[4][16 * 64];  // per-wave

    const int tid  = threadIdx.x;
    const int lane = tid & 63;
    const int wv   = tid >> 6;     // wave 0..3, owns rows q0+wv*16..+15
    const int lo   = lane & 15;
    const int hi   = lane >> 4;    // 0..3

    const int bid = blockIdx.x;          // 0..1023
    const int qt  = 31 - (bid >> 5);     // heavy q-tiles dispatched first
    const int bh  = bid & 31;
    const int q0  = qt * 64;

    const size_t base = (size_t)bh * (S_ * D_);
    const float* Q = qg + base;
    const float* K = kg + base;
    const float* V = vg + base;
    float*       O = og + base;

    // ---- Q fragments (A-layout), pre-scaled by 1/sqrt(64) ----
    bf16x8 qf[2];
    {
        const float* Qr = Q + (size_t)(q0 + wv * 16 + lo) * D_;
        #pragma unroll
        for (int c = 0; c < 2; ++c) {
            const int d0 = c * 32 + hi * 8;
            f32x4 a = *(const f32x4*)(Qr + d0);
            f32x4 b = *(const f32x4*)(Qr + d0 + 4);
            bf16x8 f;
            #pragma unroll
            for (int j = 0; j < 4; ++j) {
                f[j]     = (__bf16)(a[j] * 0.125f);
                f[4 + j] = (__bf16)(b[j] * 0.125f);
            }
            qf[c] = f;
        }
    }

    f32x4 acc[4];
    float m_r[4], l_r[4];
    #pragma unroll
    for (int i = 0; i < 4; ++i) {
        acc[i] = (f32x4){0.f, 0.f, 0.f, 0.f};
        m_r[i] = -1e30f;
        l_r[i] = 0.f;   // per-lane partial; reduced across lo-lanes at epilogue
    }

    // staging maps
    const int kk = tid >> 2;          // K: key row 0..63
    const int kd = (tid & 3) * 16;    // K: d base (16 floats per thread)
    const int vk = (tid & 15) * 4;    // V: key base (4 keys)  -> conflict-free transpose writes
    const int vd = (tid >> 4) * 4;    // V: d base (4 floats)

    const int nt = qt + 1;

    // ---- prologue: issue loads for tile 0 ----
    f32x4 rk[4], rv[4];
    {
        const float* Kp = K + (size_t)kk * D_ + kd;
        #pragma unroll
        for (int i = 0; i < 4; ++i) rk[i] = *(const f32x4*)(Kp + 4 * i);
        const float* Vp = V + (size_t)vk * D_ + vd;
        #pragma unroll
        for (int i = 0; i < 4; ++i) rv[i] = *(const f32x4*)(Vp + (size_t)i * D_);
    }

    for (int t = 0; t < nt; ++t) {
        const int buf = t & 1;
        // ---- convert + write staged regs (tile t) into LDS ----
        {
            const unsigned swzk = (kk & 7) << 4;
            bf16x8 w0, w1;
            #pragma unroll
            for (int j = 0; j < 4; ++j) {
                w0[j]     = (__bf16)rk[0][j];
                w0[4 + j] = (__bf16)rk[1][j];
                w1[j]     = (__bf16)rk[2][j];
                w1[4 + j] = (__bf16)rk[3][j];
            }
            *(bf16x8*)(&K_lds[buf][kk * 64 + ((((unsigned)(2 * kd)) ^ swzk) >> 1)])      = w0;
            *(bf16x8*)(&K_lds[buf][kk * 64 + ((((unsigned)(2 * kd + 16)) ^ swzk) >> 1)]) = w1;
            #pragma unroll
            for (int j = 0; j < 4; ++j) {
                const int d = vd + j;
                bf16x4 wt;
                #pragma unroll
                for (int i = 0; i < 4; ++i) wt[i] = (__bf16)rv[i][j];
                *(bf16x4*)(&V_lds[buf][d * 64 + ((((unsigned)(2 * vk)) ^ ((d & 7) << 4)) >> 1)]) = wt;
            }
        }
        __syncthreads();

        // ---- issue global loads for tile t+1 (hidden under compute) ----
        if (t + 1 < nt) {
            const int kv1 = (t + 1) * 64;
            const float* Kp = K + (size_t)(kv1 + kk) * D_ + kd;
            #pragma unroll
            for (int i = 0; i < 4; ++i) rk[i] = *(const f32x4*)(Kp + 4 * i);
            const float* Vp = V + (size_t)(kv1 + vk) * D_ + vd;
            #pragma unroll
            for (int i = 0; i < 4; ++i) rv[i] = *(const f32x4*)(Vp + (size_t)i * D_);
        }

        // ---- QK^T ----
        const bool diag = (t == qt);
        float sv[4][4];
        #pragma unroll
        for (int kb = 0; kb < 4; ++kb) {
            const int key = kb * 16 + lo;
            const unsigned sw = (key & 7) << 4;
            bf16x8 kf0 = *(const bf16x8*)(&K_lds[buf][key * 64 + ((((unsigned)(hi * 16)) ^ sw) >> 1)]);
            bf16x8 kf1 = *(const bf16x8*)(&K_lds[buf][key * 64 + ((((unsigned)(64 + hi * 16)) ^ sw) >> 1)]);
            f32x4 s = {0.f, 0.f, 0.f, 0.f};
            s = __builtin_amdgcn_mfma_f32_16x16x32_bf16(qf[0], kf0, s, 0, 0, 0);
            s = __builtin_amdgcn_mfma_f32_16x16x32_bf16(qf[1], kf1, s, 0, 0, 0);
            #pragma unroll
            for (int r = 0; r < 4; ++r) {
                float x = s[r];
                if (diag && key > wv * 16 + hi * 4 + r) x = -1e30f;
                sv[kb][r] = x;
            }
        }

        // ---- online softmax (max-reduce only; l kept per-lane) ----
        #pragma unroll
        for (int r = 0; r < 4; ++r) {
            float mx = fmaxf(fmaxf(sv[0][r], sv[1][r]), fmaxf(sv[2][r], sv[3][r]));
            mx = fmaxf(mx, __shfl_xor(mx, 1));
            mx = fmaxf(mx, __shfl_xor(mx, 2));
            mx = fmaxf(mx, __shfl_xor(mx, 4));
            mx = fmaxf(mx, __shfl_xor(mx, 8));
            const float mold = m_r[r];
            const float newm = fmaxf(mold, mx);
            const float corr = __expf(mold - newm);
            m_r[r] = newm;
            const int prow = hi * 4 + r;
            float ps = 0.f;
            #pragma unroll
            for (int kb = 0; kb < 4; ++kb) {
                const float p = __expf(sv[kb][r] - newm);
                ps += p;
                P_lds[wv][prow * 64 + ((((unsigned)(kb * 32 + lo * 2)) ^ ((prow & 7) << 4)) >> 1)] = (__bf16)p;
            }
            l_r[r] = l_r[r] * corr + ps;
            #pragma unroll
            for (int db = 0; db < 4; ++db) acc[db][r] *= corr;
        }

        // ---- PV ----
        bf16x8 pa[2];
        #pragma unroll
        for (int c = 0; c < 2; ++c)
            pa[c] = *(const bf16x8*)(&P_lds[wv][lo * 64 + ((((unsigned)(c * 64 + hi * 16)) ^ ((lo & 7) << 4)) >> 1)]);
        #pragma unroll
        for (int db = 0; db < 4; ++db) {
            const int d = db * 16 + lo;
            const unsigned sw = (d & 7) << 4;
            #pragma unroll
            for (int c = 0; c < 2; ++c) {
                bf16x8 vb = *(const bf16x8*)(&V_lds[buf][d * 64 + ((((unsigned)(c * 64 + hi * 16)) ^ sw) >> 1)]);
                acc[db] = __builtin_amdgcn_mfma_f32_16x16x32_bf16(pa[c], vb, acc[db], 0, 0, 0);
            }
        }
        // NOTE: no second barrier — double buffering makes next-iter writes safe:
        // a wave reaching iter t+2's write has passed barrier t+1, which implies
        // every wave finished compute of tile t (program order).
    }

    // ---- epilogue: reduce l across the 16 lo-lanes, normalize, store ----
    #pragma unroll
    for (int r = 0; r < 4; ++r) {
        float ls = l_r[r];
        ls += __shfl_xor(ls, 1);
        ls += __shfl_xor(ls, 2);
        ls += __shfl_xor(ls, 4);
        ls += __shfl_xor(ls, 8);
        const float inv = 1.0f / ls;
        const int row = q0 + wv * 16 + hi * 4 + r;
        float* Or = O + (size_t)row * D_;
        #pragma unroll
        for (int db = 0; db < 4; ++db)
            Or[db * 16 + lo] = acc[db][r] * inv;
    }
}

extern "C" void kernel_launch(void* const* d_in, const int* in_sizes, int n_in,
                              void* d_out, int out_size, void* d_ws, size_t ws_size,
                              hipStream_t stream) {
    const float* q = (const float*)d_in[0];
    const float* k = (const float*)d_in[1];
    const float* v = (const float*)d_in[2];
    float* out = (float*)d_out;
    dim3 grid(1024, 1, 1);
    dim3 block(256, 1, 1);
    fa_fwd<<<grid, block, 0, stream>>>(q, k, v, out);
}

// Round 5
// 54.951 us; speedup vs baseline: 2.2222x; 2.1039x over previous
//
#include <hip/hip_runtime.h>

#define S_ 2048
#define D_ 64

typedef __bf16 bf16x4 __attribute__((ext_vector_type(4)));
typedef __bf16 bf16x8 __attribute__((ext_vector_type(8)));
typedef float f32x4 __attribute__((ext_vector_type(4)));
typedef float f32x16 __attribute__((ext_vector_type(16)));

__global__ __launch_bounds__(256, 2)
void fa_fwd(const float* __restrict__ qg, const float* __restrict__ kg,
            const float* __restrict__ vg, float* __restrict__ og) {
    __shared__ __attribute__((aligned(16))) __bf16 K_lds[2][64 * 64];   // [key][d]
    __shared__ __attribute__((aligned(16))) __bf16 V_lds[2][64 * 64];   // [d][key]
    __shared__ __attribute__((aligned(16))) __bf16 P_lds[4][32 * 64];   // per-wave [q][key]

    const int tid  = threadIdx.x;
    const int lane = tid & 63;
    const int wv   = tid >> 6;
    const int cq   = lane & 31;   // q-column this lane owns in all fragments
    const int h    = lane >> 5;   // half-wave index

    const int bid = blockIdx.x;          // 0..511
    const int qt  = 15 - (bid >> 5);     // heavy q-tiles first
    const int bh  = bid & 31;
    const int q0w = qt * 128 + wv * 32;  // this wave's 32 q-rows

    const size_t base = (size_t)bh * (S_ * D_);
    const float* Q = qg + base;
    const float* K = kg + base;
    const float* V = vg + base;
    float*       O = og + base;

    // ---- Q fragments (B-operand: lane holds Q[q0w+cq][c*16+8h+j]), scaled 1/8 ----
    bf16x8 qf[4];
    {
        const float* Qr = Q + (size_t)(q0w + cq) * D_;
        #pragma unroll
        for (int c = 0; c < 4; ++c) {
            const int d0 = c * 16 + h * 8;
            f32x4 a = *(const f32x4*)(Qr + d0);
            f32x4 b = *(const f32x4*)(Qr + d0 + 4);
            bf16x8 f;
            #pragma unroll
            for (int j = 0; j < 4; ++j) {
                f[j]     = (__bf16)(a[j] * 0.125f);
                f[4 + j] = (__bf16)(b[j] * 0.125f);
            }
            qf[c] = f;
        }
    }

    f32x16 acc0, acc1;  // O^T accumulators, d-blocks 0/1; lane's q = cq
    #pragma unroll
    for (int i = 0; i < 16; ++i) { acc0[i] = 0.f; acc1[i] = 0.f; }
    float m_r = -1e30f, l_r = 0.f;  // running max / per-half partial sum

    // staging maps
    const int kk = tid >> 2;          // K row
    const int kd = (tid & 3) * 16;    // K d-base (16 floats)
    const int vk = (tid & 15) * 4;    // V key-base
    const int vd = (tid >> 4) * 4;    // V d-base
    const int nt = 2 * qt + 2;
    const int tdiag = q0w >> 6;
    const unsigned swq = (unsigned)((cq & 7) << 4);

    // ---- prologue loads (tile 0) ----
    f32x4 rk[4], rv[4];
    {
        const float* Kp = K + (size_t)kk * D_ + kd;
        #pragma unroll
        for (int i = 0; i < 4; ++i) rk[i] = *(const f32x4*)(Kp + 4 * i);
        const float* Vp = V + (size_t)vk * D_ + vd;
        #pragma unroll
        for (int i = 0; i < 4; ++i) rv[i] = *(const f32x4*)(Vp + (size_t)i * D_);
    }

    for (int t = 0; t < nt; ++t) {
        const int buf = t & 1;
        // ---- convert + LDS write of staged tile t ----
        {
            const unsigned swzk = (unsigned)((kk & 7) << 4);
            bf16x8 w0, w1;
            #pragma unroll
            for (int j = 0; j < 4; ++j) {
                w0[j]     = (__bf16)rk[0][j];
                w0[4 + j] = (__bf16)rk[1][j];
                w1[j]     = (__bf16)rk[2][j];
                w1[4 + j] = (__bf16)rk[3][j];
            }
            *(bf16x8*)(&K_lds[buf][kk * 64 + ((((unsigned)(2 * kd)) ^ swzk) >> 1)])      = w0;
            *(bf16x8*)(&K_lds[buf][kk * 64 + ((((unsigned)(2 * kd + 16)) ^ swzk) >> 1)]) = w1;
            #pragma unroll
            for (int j = 0; j < 4; ++j) {
                const int d = vd + j;
                bf16x4 wt;
                #pragma unroll
                for (int i = 0; i < 4; ++i) wt[i] = (__bf16)rv[i][j];
                *(bf16x4*)(&V_lds[buf][d * 64 + ((((unsigned)(2 * vk)) ^ ((unsigned)((d & 7) << 4))) >> 1)]) = wt;
            }
        }
        __syncthreads();

        // ---- prefetch tile t+1 (flies under compute) ----
        if (t + 1 < nt) {
            const int kv1 = (t + 1) * 64;
            const float* Kp = K + (size_t)(kv1 + kk) * D_ + kd;
            #pragma unroll
            for (int i = 0; i < 4; ++i) rk[i] = *(const f32x4*)(Kp + 4 * i);
            const float* Vp = V + (size_t)(kv1 + vk) * D_ + vd;
            #pragma unroll
            for (int i = 0; i < 4; ++i) rv[i] = *(const f32x4*)(Vp + (size_t)i * D_);
        }

        if (t <= tdiag) {
            // ---- QK^T, swapped: S^T[key][q], q = cq lane-local ----
            f32x16 s0, s1;
            #pragma unroll
            for (int i = 0; i < 16; ++i) { s0[i] = 0.f; s1[i] = 0.f; }
            __builtin_amdgcn_s_setprio(1);
            #pragma unroll
            for (int c = 0; c < 4; ++c) {
                const unsigned co = (unsigned)(c * 32 + h * 16);
                bf16x8 a0 = *(const bf16x8*)(&K_lds[buf][cq * 64 + ((co ^ swq) >> 1)]);
                bf16x8 a1 = *(const bf16x8*)(&K_lds[buf][(32 + cq) * 64 + ((co ^ swq) >> 1)]);
                s0 = __builtin_amdgcn_mfma_f32_32x32x16_bf16(a0, qf[c], s0, 0, 0, 0);
                s1 = __builtin_amdgcn_mfma_f32_32x32x16_bf16(a1, qf[c], s1, 0, 0, 0);
            }
            __builtin_amdgcn_s_setprio(0);

            // ---- causal mask (diagonal tile only) ----
            // C/D map: row = (reg&3) + 8*(reg>>2) + 4*h, col = cq   [m74/m101]
            if (t == tdiag) {
                const int q = q0w + cq;
                const int kvb = t * 64 + 4 * h;
                #pragma unroll
                for (int reg = 0; reg < 16; ++reg) {
                    const int key = kvb + (reg & 3) + 8 * (reg >> 2);
                    if (key > q)      s0[reg] = -1e30f;
                    if (key + 32 > q) s1[reg] = -1e30f;
                }
            }

            // ---- row max: in-lane tree + one half-exchange shuffle ----
            float t8[8];
            #pragma unroll
            for (int i = 0; i < 8; ++i)
                t8[i] = fmaxf(fmaxf(s0[i], s0[i + 8]), fmaxf(s1[i], s1[i + 8]));
            float mx = fmaxf(fmaxf(fmaxf(t8[0], t8[4]), fmaxf(t8[1], t8[5])),
                             fmaxf(fmaxf(t8[2], t8[6]), fmaxf(t8[3], t8[7])));
            mx = fmaxf(mx, __shfl_xor(mx, 32));

            const float mnew = fmaxf(m_r, mx);
            const float corr = __expf(m_r - mnew);
            m_r = mnew;
            float ps = 0.f;
            #pragma unroll
            for (int i = 0; i < 16; ++i) { s0[i] = __expf(s0[i] - mnew); ps += s0[i]; }
            #pragma unroll
            for (int i = 0; i < 16; ++i) { s1[i] = __expf(s1[i] - mnew); ps += s1[i]; }
            l_r = l_r * corr + ps;
            #pragma unroll
            for (int i = 0; i < 16; ++i) { acc0[i] *= corr; acc1[i] *= corr; }

            // ---- P -> bf16, park in wave-private LDS [q][key] (swizzled) ----
            // s0 quad m holds keys 8m+4h+0..3 (consecutive) for row q=cq
            {
                __bf16* Pw = &P_lds[wv][cq * 64];
                #pragma unroll
                for (int m = 0; m < 4; ++m) {
                    bf16x4 wa, wb;
                    #pragma unroll
                    for (int j = 0; j < 4; ++j) {
                        wa[j] = (__bf16)s0[4 * m + j];
                        wb[j] = (__bf16)s1[4 * m + j];
                    }
                    *(bf16x4*)(&Pw[((((unsigned)(16 * m + 8 * h)) ^ swq) >> 1)])      = wa;
                    *(bf16x4*)(&Pw[((((unsigned)(64 + 16 * m + 8 * h)) ^ swq) >> 1)]) = wb;
                }
            }

            // ---- PV, swapped: O^T[d][q] += V^T · P^T ----
            __builtin_amdgcn_s_setprio(1);
            const __bf16* Pw = &P_lds[wv][cq * 64];
            #pragma unroll
            for (int ks = 0; ks < 4; ++ks) {
                const unsigned co = (unsigned)(ks * 32 + h * 16);
                bf16x8 pb  = *(const bf16x8*)(&Pw[((co ^ swq) >> 1)]);
                bf16x8 va0 = *(const bf16x8*)(&V_lds[buf][cq * 64 + ((co ^ swq) >> 1)]);
                bf16x8 va1 = *(const bf16x8*)(&V_lds[buf][(32 + cq) * 64 + ((co ^ swq) >> 1)]);
                acc0 = __builtin_amdgcn_mfma_f32_32x32x16_bf16(va0, pb, acc0, 0, 0, 0);
                acc1 = __builtin_amdgcn_mfma_f32_32x32x16_bf16(va1, pb, acc1, 0, 0, 0);
            }
            __builtin_amdgcn_s_setprio(0);
        }
    }

    // ---- epilogue: combine l halves, normalize, store 16B chunks ----
    const float lsum = l_r + __shfl_xor(l_r, 32);
    const float inv = 1.0f / lsum;
    float* Or = O + (size_t)(q0w + cq) * D_;
    #pragma unroll
    for (int rq = 0; rq < 4; ++rq) {
        f32x4 w0, w1;
        #pragma unroll
        for (int i = 0; i < 4; ++i) {
            w0[i] = acc0[4 * rq + i] * inv;
            w1[i] = acc1[4 * rq + i] * inv;
        }
        *(f32x4*)(Or + 8 * rq + 4 * h)      = w0;
        *(f32x4*)(Or + 32 + 8 * rq + 4 * h) = w1;
    }
}

extern "C" void kernel_launch(void* const* d_in, const int* in_sizes, int n_in,
                              void* d_out, int out_size, void* d_ws, size_t ws_size,
                              hipStream_t stream) {
    const float* q = (const float*)d_in[0];
    const float* k = (const float*)d_in[1];
    const float* v = (const float*)d_in[2];
    float* out = (float*)d_out;
    dim3 grid(512, 1, 1);
    dim3 block(256, 1, 1);
    fa_fwd<<<grid, block, 0, stream>>>(q, k, v, out);
}